// Round 10
// baseline (136.338 us; speedup 1.0000x reference)
//
#include <hip/hip_runtime.h>
#include <stdint.h>

// Problem constants (match reference)
#define BATCH    256
#define MPTS     512
#define KNN      33
#define RADIUS_F 5.0f
#define EDGES    (BATCH * MPTS * KNN)   // 4,325,376 edges; out = 4*EDGES float32

// 1024-thread blocks: 16 waves/block, 2 blocks/CU (512 blocks over 256 CUs).
// Tests the residency hypothesis: grids of 8 small blocks/CU measured only
// ~34% occupancy (rounds 5-9) though all static limits allowed 100%; with
// 16 waves/block the scheduler only needs 2 co-resident blocks per CU.
#define BLOCKS_PER_GRAPH 2
#define ROWS_PER_BLOCK   256            // MPTS / BLOCKS_PER_GRAPH
#define THREADS          1024
#define WAVES_PER_BLOCK  16             // THREADS / 64
#define SLOT_STRIDE      72             // 64 slots + pad (shifts region base banks)

typedef float f32x2 __attribute__((ext_vector_type(2)));
typedef unsigned short u16x2 __attribute__((ext_vector_type(2)));

#if defined(__has_builtin)
#if __has_builtin(__builtin_elementwise_fma)
#define HAVE_PKFMA 1
#endif
#endif

// Packed unsigned 16-bit min/max — lowers to v_pk_min_u16 / v_pk_max_u16
// (VOP3P). Both halves carry independent rows; one instruction serves both.
static __device__ __forceinline__ uint32_t pk_min_u16(uint32_t a, uint32_t b) {
    const u16x2 r = __builtin_elementwise_min(__builtin_bit_cast(u16x2, a),
                                              __builtin_bit_cast(u16x2, b));
    return __builtin_bit_cast(uint32_t, r);
}
static __device__ __forceinline__ uint32_t pk_max_u16(uint32_t a, uint32_t b) {
    const u16x2 r = __builtin_elementwise_max(__builtin_bit_cast(u16x2, a),
                                              __builtin_bit_cast(u16x2, b));
    return __builtin_bit_cast(uint32_t, r);
}

// ---------------------------------------------------------------------------
// Cross-lane xor-shuffle, LDS-PIPE hybrid (validated round 8: 75 -> 70 us).
// VALU-pipe-bound kernel; J=4/16/32 shuffles ride the LDS pipe:
//   J=1,2  : quad_perm DPP (1 VALU — already minimal)
//   J=8    : row_ror:8 DPP (1 VALU)
//   J=4    : ds_swizzle BitMode xor4  (0x101F)
//   J=16   : ds_swizzle BitMode xor16 (0x401F)
//   J=32   : __shfl_xor 32 (ds_bpermute)
template <int J>
static __device__ __forceinline__ uint32_t shx32(uint32_t x) {
    if constexpr (J == 1) {
        return (uint32_t)__builtin_amdgcn_update_dpp(0, (int)x, 0xB1, 0xF, 0xF, false);  // quad_perm [1,0,3,2]
    } else if constexpr (J == 2) {
        return (uint32_t)__builtin_amdgcn_update_dpp(0, (int)x, 0x4E, 0xF, 0xF, false);  // quad_perm [2,3,0,1]
    } else if constexpr (J == 4) {
        return (uint32_t)__builtin_amdgcn_ds_swizzle((int)x, 0x101F);                    // xor4 (LDS pipe)
    } else if constexpr (J == 8) {
        return (uint32_t)__builtin_amdgcn_update_dpp(0, (int)x, 0x128, 0xF, 0xF, false); // row_ror:8
    } else if constexpr (J == 16) {
        return (uint32_t)__builtin_amdgcn_ds_swizzle((int)x, 0x401F);                    // xor16 (LDS pipe)
    } else {
        return (uint32_t)__shfl_xor((int)x, 32, 64);                                     // xor32 (ds_bpermute)
    }
}

// One bitonic compare-exchange stage at distance J on a u32 key.
// lowJ = ((lane&J)==0), up = ((lane&K)==0); km combine is SALU.
template <int J>
static __device__ __forceinline__ void ce32(uint32_t& v, bool lowJ, bool up) {
    const uint32_t p = shx32<J>(v);
    const bool km = (lowJ == up);      // this element keeps the min of the pair
    v = ((v < p) == km) ? v : p;
}

// Packed CE: both 16-bit halves exchange with the same lane-direction
// predicates — one pk_min + one pk_max + one cndmask serves TWO rows.
template <int J>
static __device__ __forceinline__ void cePk(uint32_t& v, bool lowJ, bool up) {
    const uint32_t p    = shx32<J>(v);
    const uint32_t vmin = pk_min_u16(v, p);
    const uint32_t vmax = pk_max_u16(v, p);
    v = (lowJ == up) ? vmin : vmax;
}

// Dual ascending bitonic sort of 64 u32 keys (one per lane), two independent
// chains interleaved — the chains hide each other's LDS-shuffle latency.
static __device__ __forceinline__ void bsort64d(uint32_t& a, uint32_t& b,
        bool l1, bool l2, bool l4, bool l8, bool l16, bool l32) {
#define C2(J, L, U) do { ce32<J>(a, L, U); ce32<J>(b, L, U); } while (0)
    C2(1, l1, l2);
    C2(2, l2, l4);   C2(1, l1, l4);
    C2(4, l4, l8);   C2(2, l2, l8);   C2(1, l1, l8);
    C2(8, l8, l16);  C2(4, l4, l16);  C2(2, l2, l16);  C2(1, l1, l16);
    C2(16, l16, l32); C2(8, l8, l32); C2(4, l4, l32);  C2(2, l2, l32); C2(1, l1, l32);
    C2(32, l32, true); C2(16, l16, true); C2(8, l8, true);
    C2(4, l4, true);   C2(2, l2, true);   C2(1, l1, true);
#undef C2
}

// Packed ascending bitonic sort of 64 lanes x two independent 16-bit rows.
static __device__ __forceinline__ uint32_t bsort64pk(uint32_t v,
        bool l1, bool l2, bool l4, bool l8, bool l16, bool l32) {
    cePk<1>(v, l1, l2);
    cePk<2>(v, l2, l4);   cePk<1>(v, l1, l4);
    cePk<4>(v, l4, l8);   cePk<2>(v, l2, l8);   cePk<1>(v, l1, l8);
    cePk<8>(v, l8, l16);  cePk<4>(v, l4, l16);  cePk<2>(v, l2, l16);  cePk<1>(v, l1, l16);
    cePk<16>(v, l16, l32); cePk<8>(v, l8, l32); cePk<4>(v, l4, l32);  cePk<2>(v, l2, l32); cePk<1>(v, l1, l32);
    cePk<32>(v, l32, true); cePk<16>(v, l16, true); cePk<8>(v, l8, true);
    cePk<4>(v, l4, true);   cePk<2>(v, l2, true);   cePk<1>(v, l1, true);
    return v;
}

// Wave-wide inclusive scan (classic GCN DPP ladder). Lane 63 holds the total.
static __device__ __forceinline__ uint32_t wave_incl_scan(uint32_t x) {
    x += (uint32_t)__builtin_amdgcn_update_dpp(0, (int)x, 0x111, 0xF, 0xF, false);
    x += (uint32_t)__builtin_amdgcn_update_dpp(0, (int)x, 0x112, 0xF, 0xF, false);
    x += (uint32_t)__builtin_amdgcn_update_dpp(0, (int)x, 0x114, 0xF, 0xF, false);
    x += (uint32_t)__builtin_amdgcn_update_dpp(0, (int)x, 0x118, 0xF, 0xF, false);
    x += (uint32_t)__builtin_amdgcn_update_dpp(0, (int)x, 0x142, 0xA, 0xF, false);
    x += (uint32_t)__builtin_amdgcn_update_dpp(0, (int)x, 0x143, 0xC, 0xF, false);
    return x;
}

__global__ void __launch_bounds__(THREADS)
InteractionModule_50483045597845_kernel(const float* __restrict__ pos,
                                        float* __restrict__ out) {
    // 8 KB: one graph's 512 points as (x, y, z, |p|^2) — staged once,
    // amortized over 16 waves (4x better than the 256-thread version).
    __shared__ float4 spt[MPTS];
    // 9 KB: per-(wave,row) survivor slots, u32 key = (d2bits & ~0x1FF) | n.
    __shared__ uint32_t slots[WAVES_PER_BLOCK * 2][SLOT_STRIDE];

    const int graph = blockIdx.x / BLOCKS_PER_GRAPH;
    const int slice = blockIdx.x - graph * BLOCKS_PER_GRAPH;
    const int tid   = (int)threadIdx.x;
    const int gbase = graph * MPTS;

    for (int p = tid; p < MPTS; p += THREADS) {
        const float* pp = pos + (size_t)(gbase + p) * 3;
        const float x = pp[0], y = pp[1], z = pp[2];
        // fma-chain |p|^2 — matches dot() below exactly so self-edge d2 == 0
        const float sq = __builtin_fmaf(x, x, __builtin_fmaf(y, y, __fmul_rn(z, z)));
        spt[p] = make_float4(x, y, z, sq);
    }
    __syncthreads();

    const int lane = tid & 63;
    const int wave = tid >> 6;

    // hoisted lane-bit predicates (live as sgpr masks)
    const bool l1  = (lane & 1) == 0;
    const bool l2  = (lane & 2) == 0;
    const bool l4  = (lane & 4) == 0;
    const bool l8  = (lane & 8) == 0;
    const bool l16 = (lane & 16) == 0;
    const bool l32 = (lane & 32) == 0;

    // Emit one edge: dist/mask recomputed exactly as numpy fp32 (rn ops, same
    // order) — bit-identical given identical (src,dst).
    auto emitOne = [&](uint32_t key, float cx, float cy, float cz, int mRow, int k) {
        const int kept  = (int)(key & 0x1FFu);
        const float4 q  = spt[kept];
        const float dx  = __fsub_rn(q.x, cx);
        const float dy  = __fsub_rn(q.y, cy);
        const float dz  = __fsub_rn(q.z, cz);
        const float ss  = __fadd_rn(__fadd_rn(__fmul_rn(dx, dx),
                                              __fmul_rn(dy, dy)),
                                    __fmul_rn(dz, dz));
        const float dist  = (ss > 0.0f) ? __fsqrt_rn(ss) : 0.0f;
        const float maskv = (dist <= RADIUS_F) ? 1.0f : 0.0f;
        const size_t e    = (size_t)mRow * KNN + (size_t)k;
        out[e]                     = (float)(gbase + kept);
        out[(size_t)EDGES + e]     = (float)mRow;
        out[2 * (size_t)EDGES + e] = dist;
        out[3 * (size_t)EDGES + e] = maskv;
    };

    // Merged full-wave epilogue for a row-pair (validated rounds 4-9):
    // 66 edges over 64 lanes. pass 1: lanes 0..32 -> row X edge k=lane;
    // lanes 33..63 -> row Y edge k=lane-33 (vY pulled via bpermute).
    // pass 2: lanes 31,32 emit row Y edges 31,32 (they hold vY rank 31,32).
    auto emitPair = [&](uint32_t vX, uint32_t vY, const float4 pX,
                        const float4 pY, int mRowX, int mRowY) {
        const bool isX = (lane < KNN);
        const int  k1  = isX ? lane : (lane - KNN);
        const uint32_t vYs = (uint32_t)__builtin_amdgcn_ds_bpermute(
            (((lane - KNN) & 63) << 2), (int)vY);
        const uint32_t key1 = isX ? vX : vYs;
        const float cx = isX ? pX.x : pY.x;
        const float cy = isX ? pX.y : pY.y;
        const float cz = isX ? pX.z : pY.z;
        const int mRow1 = isX ? mRowX : mRowY;
        emitOne(key1, cx, cy, cz, mRow1, k1);
        if ((unsigned)(lane - 31) < 2u) {
            emitOne(vY, pY.x, pY.y, pY.z, mRowY, lane);
        }
    };

    // Rare path (>64 survivors with the 16-bit-rounded head pivot, <1% of
    // rows): keys are UNIQUE (candidate id in low 9 bits), so the minimal
    // valid pivot has element-count EXACTLY 33. Exact u32 bisection.
    auto refineRow = [&](const uint32_t* sk, uint32_t& P,
                         uint32_t& cnt, uint32_t& incl, uint32_t& total) {
        uint32_t lo = 0u, hi = P;
        while (lo < hi) {
            const uint32_t mid = lo + ((hi - lo) >> 1);
            uint32_t c = 0;
            #pragma unroll
            for (int j = 0; j < 8; ++j) c += (sk[j] <= mid) ? 1u : 0u;
            const uint32_t t =
                (uint32_t)__builtin_amdgcn_readlane((int)wave_incl_scan(c), 63);
            if (t < KNN) lo = mid + 1; else hi = mid;
        }
        P = hi;
        cnt = 0;
        #pragma unroll
        for (int j = 0; j < 8; ++j) cnt += (sk[j] <= P) ? 1u : 0u;
        incl  = wave_incl_scan(cnt);   // lane63 total == 33 by key uniqueness
        total = KNN;
    };

    // 8 outer iterations × (16 waves × 2 rows) = 256 rows per block.
    #pragma unroll 1
    for (int it = 0; it < ROWS_PER_BLOCK / (WAVES_PER_BLOCK * 2); ++it) {
        const int mA = slice * ROWS_PER_BLOCK + it * (WAVES_PER_BLOCK * 2) + wave;
        const int mB = mA + WAVES_PER_BLOCK;

        const float4 pa = spt[mA];
        const float4 pb = spt[mB];

        // --- distance/key phase, rows A,B packed as v_pk f32x2 -------------
        // Lane holds candidates n = lane + 64*j for BOTH rows (shared q load).
        // u32 key = (d2bits & ~0x1FF) | n: candidate id in low 9 bits,
        // 512-ulp d2 truncation (tie flips tolerated; dist recomputed
        // exactly). No max(d2,0): self-edge d2 is exactly +0 by identical
        // fma-chain construction; a negative near-zero d2 (coincident
        // points, ~never on this data) sorts to the tail — same tolerated
        // tie class. Packed ops are IEEE-RN per component.
        uint32_t sA[8], sB[8];
        {
#ifdef HAVE_PKFMA
            const f32x2 px = {pa.x, pb.x}, py = {pa.y, pb.y};
            const f32x2 pz = {pa.z, pb.z}, pw = {pa.w, pb.w};
            const f32x2 m2 = {-2.0f, -2.0f};
#endif
            #pragma unroll
            for (int j = 0; j < 8; ++j) {
                const int n = lane + (j << 6);
                const float4 q = spt[n];
#ifdef HAVE_PKFMA
                const f32x2 qx = {q.x, q.x}, qy = {q.y, q.y};
                const f32x2 qz = {q.z, q.z}, qw = {q.w, q.w};
                const f32x2 dot = __builtin_elementwise_fma(px, qx,
                                  __builtin_elementwise_fma(py, qy, pz * qz));
                const f32x2 d2  = __builtin_elementwise_fma(m2, dot, pw + qw);
                const float d2A = d2[0];
                const float d2B = d2[1];
#else
                const float dotA = __builtin_fmaf(pa.x, q.x,
                                   __builtin_fmaf(pa.y, q.y, __fmul_rn(pa.z, q.z)));
                const float dotB = __builtin_fmaf(pb.x, q.x,
                                   __builtin_fmaf(pb.y, q.y, __fmul_rn(pb.z, q.z)));
                const float d2A = __builtin_fmaf(-2.0f, dotA, __fadd_rn(pa.w, q.w));
                const float d2B = __builtin_fmaf(-2.0f, dotB, __fadd_rn(pb.w, q.w));
#endif
                // canonical (m&x)|(~m&y) -> v_bfi_b32
                sA[j] = (0xFFFFFE00u & __float_as_uint(d2A)) | (0x000001FFu & (uint32_t)n);
                sB[j] = (0xFFFFFE00u & __float_as_uint(d2B)) | (0x000001FFu & (uint32_t)n);
            }
        }

        // --- per-lane heads -------------------------------------------------
        uint32_t hA = sA[0], hB = sB[0];
        #pragma unroll
        for (int j = 1; j < 8; ++j) {
            hA = sA[j] < hA ? sA[j] : hA;
            hB = sB[j] < hB ? sB[j] : hB;
        }

        // --- pivot = 33rd-smallest head, via ONE PACKED 16-bit head-sort ----
        // Both rows' heads truncated to their top 16 bits and packed into one
        // register (lo = row A, hi = row B); a single bitonic sort64 with
        // v_pk_min/max_u16 sorts both rows at once (same lane predicates).
        // floor-truncation is monotone => sorted16[32] = trunc16(h_(33));
        // P = (trunc16(h_(33)) << 16) | 0xFFFF >= h_(33), so count(<=P) >= 33
        // still holds. The 2^16-ulp round-up adds ~0.3 expected survivors
        // (d2-density near cutoff); >64 overflow handled by exact refineRow.
        uint32_t hP = (hB & 0xFFFF0000u) | (hA >> 16);
        hP = bsort64pk(hP, l1, l2, l4, l8, l16, l32);
        const uint32_t s32 = (uint32_t)__builtin_amdgcn_readlane((int)hP, 32);
        uint32_t PA = (s32 << 16) | 0xFFFFu;
        uint32_t PB = (s32 & 0xFFFF0000u) | 0xFFFFu;

        // --- dual count + ONE packed scan (halves can't carry: totals<=512) -
        uint32_t cntA = 0, cntB = 0;
        #pragma unroll
        for (int j = 0; j < 8; ++j) {
            cntA += (sA[j] <= PA) ? 1u : 0u;
            cntB += (sB[j] <= PB) ? 1u : 0u;
        }
        const uint32_t cP   = wave_incl_scan(cntA + (cntB << 16));
        const uint32_t totP = (uint32_t)__builtin_amdgcn_readlane((int)cP, 63);
        uint32_t inclA = cP & 0xFFFFu;
        uint32_t inclB = cP >> 16;
        uint32_t totalA = totP & 0xFFFFu;
        uint32_t totalB = totP >> 16;

        // rare overflow: tighten to the exact minimal pivot (=> exactly 33)
        if (__builtin_expect(totalA > 64u, 0)) refineRow(sA, PA, cntA, inclA, totalA);
        if (__builtin_expect(totalB > 64u, 0)) refineRow(sB, PB, cntB, inclB, totalB);

        const int rA = wave;
        const int rB = wave + WAVES_PER_BLOCK;
        const int mRowA = gbase + mA;
        const int mRowB = gbase + mB;

        // --- conditional (exec-masked) scatter: survivors only, dense unique
        // destinations, bank-stride 1 (u32). NO padding-init writes: lanes
        // beyond `total` are masked to +INF on the read below instead (2 VALU
        // replace 2 LDS writes and shorten the scatter->read drain).
        uint32_t dA = inclA - cntA;
        uint32_t dB = inclB - cntB;
        #pragma unroll
        for (int j = 0; j < 8; ++j) {
            const bool svA = (sA[j] <= PA);
            const bool svB = (sB[j] <= PB);
            if (svA) slots[rA][dA] = sA[j];
            if (svB) slots[rB][dB] = sB[j];
            dA += svA ? 1u : 0u;
            dB += svB ? 1u : 0u;
        }

        // same-wave producer/consumer: lgkmcnt ordering only, no barrier.
        // Positions >= total hold stale data — masked to +INF (sorts to tail).
        const uint32_t rdA = slots[rA][lane];
        const uint32_t rdB = slots[rB][lane];
        uint32_t vA = ((uint32_t)lane < totalA) ? rdA : 0xFFFFFFFFu;
        uint32_t vB = ((uint32_t)lane < totalB) ? rdB : 0xFFFFFFFFu;
        bsort64d(vA, vB, l1, l2, l4, l8, l16, l32);

        emitPair(vA, vB, pa, pb, mRowA, mRowB);
    }
}

extern "C" void kernel_launch(void* const* d_in, const int* in_sizes, int n_in,
                              void* d_out, int out_size, void* d_ws, size_t ws_size,
                              hipStream_t stream) {
    (void)in_sizes; (void)n_in; (void)out_size; (void)d_ws; (void)ws_size;
    const float* pos = (const float*)d_in[0];   // d_in[1] (batch) implied by layout
    float*       out = (float*)d_out;
    hipLaunchKernelGGL(InteractionModule_50483045597845_kernel,
                       dim3(BATCH * BLOCKS_PER_GRAPH), dim3(THREADS), 0, stream,
                       pos, out);
}

// Round 12
// 130.317 us; speedup vs baseline: 1.0462x; 1.0462x over previous
//
#include <hip/hip_runtime.h>
#include <stdint.h>

// Problem constants (match reference)
#define BATCH    256
#define MPTS     512
#define KNN      33
#define RADIUS_F 5.0f
#define EDGES    (BATCH * MPTS * KNN)   // 4,325,376 edges; out = 4*EDGES float32

#define BLOCKS_PER_GRAPH 8
#define ROWS_PER_BLOCK   64             // MPTS / BLOCKS_PER_GRAPH
#define THREADS          256
#define WAVES_PER_BLOCK  4              // THREADS / 64
#define SLOT_STRIDE      72             // 64 slots + pad (shifts region base banks)

typedef float f32x2 __attribute__((ext_vector_type(2)));
typedef unsigned short u16x2 __attribute__((ext_vector_type(2)));

#if defined(__has_builtin)
#if __has_builtin(__builtin_elementwise_fma)
#define HAVE_PKFMA 1
#endif
#endif

// Packed unsigned 16-bit min/max — lowers to v_pk_min_u16 / v_pk_max_u16
// (VOP3P). Both halves carry independent rows; one instruction serves both.
static __device__ __forceinline__ uint32_t pk_min_u16(uint32_t a, uint32_t b) {
    const u16x2 r = __builtin_elementwise_min(__builtin_bit_cast(u16x2, a),
                                              __builtin_bit_cast(u16x2, b));
    return __builtin_bit_cast(uint32_t, r);
}
static __device__ __forceinline__ uint32_t pk_max_u16(uint32_t a, uint32_t b) {
    const u16x2 r = __builtin_elementwise_max(__builtin_bit_cast(u16x2, a),
                                              __builtin_bit_cast(u16x2, b));
    return __builtin_bit_cast(uint32_t, r);
}

// ---------------------------------------------------------------------------
// Cross-lane xor-shuffle, LDS-PIPE hybrid (validated round 8: 75 -> 70 us).
// VALU-pipe-bound kernel; J=4/16/32 shuffles ride the LDS pipe:
//   J=1,2  : quad_perm DPP (1 VALU — already minimal)
//   J=8    : row_ror:8 DPP (1 VALU)
//   J=4    : ds_swizzle BitMode xor4  (0x101F)
//   J=16   : ds_swizzle BitMode xor16 (0x401F)
//   J=32   : __shfl_xor 32 (ds_bpermute)
template <int J>
static __device__ __forceinline__ uint32_t shx32(uint32_t x) {
    if constexpr (J == 1) {
        return (uint32_t)__builtin_amdgcn_update_dpp(0, (int)x, 0xB1, 0xF, 0xF, false);  // quad_perm [1,0,3,2]
    } else if constexpr (J == 2) {
        return (uint32_t)__builtin_amdgcn_update_dpp(0, (int)x, 0x4E, 0xF, 0xF, false);  // quad_perm [2,3,0,1]
    } else if constexpr (J == 4) {
        return (uint32_t)__builtin_amdgcn_ds_swizzle((int)x, 0x101F);                    // xor4 (LDS pipe)
    } else if constexpr (J == 8) {
        return (uint32_t)__builtin_amdgcn_update_dpp(0, (int)x, 0x128, 0xF, 0xF, false); // row_ror:8
    } else if constexpr (J == 16) {
        return (uint32_t)__builtin_amdgcn_ds_swizzle((int)x, 0x401F);                    // xor16 (LDS pipe)
    } else {
        return (uint32_t)__shfl_xor((int)x, 32, 64);                                     // xor32 (ds_bpermute)
    }
}

// One bitonic compare-exchange stage at distance J on a u32 key.
// lowJ = ((lane&J)==0), up = ((lane&K)==0); km combine is SALU.
template <int J>
static __device__ __forceinline__ void ce32(uint32_t& v, bool lowJ, bool up) {
    const uint32_t p = shx32<J>(v);
    const bool km = (lowJ == up);      // this element keeps the min of the pair
    v = ((v < p) == km) ? v : p;
}

// Packed CE: both 16-bit halves exchange with the same lane-direction
// predicates — one pk_min + one pk_max + one cndmask serves TWO rows.
template <int J>
static __device__ __forceinline__ void cePk(uint32_t& v, bool lowJ, bool up) {
    const uint32_t p    = shx32<J>(v);
    const uint32_t vmin = pk_min_u16(v, p);
    const uint32_t vmax = pk_max_u16(v, p);
    v = (lowJ == up) ? vmin : vmax;
}

// Dual ascending bitonic sort of 64 u32 keys (one per lane), two independent
// chains interleaved — the chains hide each other's LDS-shuffle latency.
static __device__ __forceinline__ void bsort64d(uint32_t& a, uint32_t& b,
        bool l1, bool l2, bool l4, bool l8, bool l16, bool l32) {
#define C2(J, L, U) do { ce32<J>(a, L, U); ce32<J>(b, L, U); } while (0)
    C2(1, l1, l2);
    C2(2, l2, l4);   C2(1, l1, l4);
    C2(4, l4, l8);   C2(2, l2, l8);   C2(1, l1, l8);
    C2(8, l8, l16);  C2(4, l4, l16);  C2(2, l2, l16);  C2(1, l1, l16);
    C2(16, l16, l32); C2(8, l8, l32); C2(4, l4, l32);  C2(2, l2, l32); C2(1, l1, l32);
    C2(32, l32, true); C2(16, l16, true); C2(8, l8, true);
    C2(4, l4, true);   C2(2, l2, true);   C2(1, l1, true);
#undef C2
}

// Packed ascending bitonic sort of 64 lanes x two independent 16-bit rows.
static __device__ __forceinline__ uint32_t bsort64pk(uint32_t v,
        bool l1, bool l2, bool l4, bool l8, bool l16, bool l32) {
    cePk<1>(v, l1, l2);
    cePk<2>(v, l2, l4);   cePk<1>(v, l1, l4);
    cePk<4>(v, l4, l8);   cePk<2>(v, l2, l8);   cePk<1>(v, l1, l8);
    cePk<8>(v, l8, l16);  cePk<4>(v, l4, l16);  cePk<2>(v, l2, l16);  cePk<1>(v, l1, l16);
    cePk<16>(v, l16, l32); cePk<8>(v, l8, l32); cePk<4>(v, l4, l32);  cePk<2>(v, l2, l32); cePk<1>(v, l1, l32);
    cePk<32>(v, l32, true); cePk<16>(v, l16, true); cePk<8>(v, l8, true);
    cePk<4>(v, l4, true);   cePk<2>(v, l2, true);   cePk<1>(v, l1, true);
    return v;
}

// Wave-wide inclusive scan (classic GCN DPP ladder). Lane 63 holds the total.
static __device__ __forceinline__ uint32_t wave_incl_scan(uint32_t x) {
    x += (uint32_t)__builtin_amdgcn_update_dpp(0, (int)x, 0x111, 0xF, 0xF, false);
    x += (uint32_t)__builtin_amdgcn_update_dpp(0, (int)x, 0x112, 0xF, 0xF, false);
    x += (uint32_t)__builtin_amdgcn_update_dpp(0, (int)x, 0x114, 0xF, 0xF, false);
    x += (uint32_t)__builtin_amdgcn_update_dpp(0, (int)x, 0x118, 0xF, 0xF, false);
    x += (uint32_t)__builtin_amdgcn_update_dpp(0, (int)x, 0x142, 0xA, 0xF, false);
    x += (uint32_t)__builtin_amdgcn_update_dpp(0, (int)x, 0x143, 0xC, 0xF, false);
    return x;
}

__global__ void __launch_bounds__(THREADS)
InteractionModule_50483045597845_kernel(const float* __restrict__ pos,
                                        float* __restrict__ out) {
    // 8 KB: one graph's 512 points as (x, y, z, |p|^2)
    __shared__ float4 spt[MPTS];
    // 2.25 KB: per-(wave,row) survivor slots, u32 key = (d2bits & ~0x1FF) | n.
    __shared__ uint32_t slots[WAVES_PER_BLOCK * 2][SLOT_STRIDE];

    const int graph = blockIdx.x / BLOCKS_PER_GRAPH;
    const int slice = blockIdx.x - graph * BLOCKS_PER_GRAPH;
    const int tid   = (int)threadIdx.x;
    const int gbase = graph * MPTS;

    for (int p = tid; p < MPTS; p += THREADS) {
        const float* pp = pos + (size_t)(gbase + p) * 3;
        const float x = pp[0], y = pp[1], z = pp[2];
        // fma-chain |p|^2 — matches dot() below exactly so self-edge d2 == 0
        const float sq = __builtin_fmaf(x, x, __builtin_fmaf(y, y, __fmul_rn(z, z)));
        spt[p] = make_float4(x, y, z, sq);
    }
    __syncthreads();

    const int lane = tid & 63;
    const int wave = tid >> 6;

    // hoisted lane-bit predicates (live as sgpr masks)
    const bool l1  = (lane & 1) == 0;
    const bool l2  = (lane & 2) == 0;
    const bool l4  = (lane & 4) == 0;
    const bool l8  = (lane & 8) == 0;
    const bool l16 = (lane & 16) == 0;
    const bool l32 = (lane & 32) == 0;

    // Merged full-wave epilogue for a row-pair (structure validated r4-r10),
    // SGPR-BASE ADDRESSED: the four output-plane base pointers are wave-
    // uniform given mRowA (readfirstlane -> SALU pointer math), and row B
    // lives at a fixed +132-element offset (mRowB = mRowA+4, x33). Each
    // store becomes saddr + one shared 32-bit lane index — this deletes the
    // per-lane 64-bit address chains (~30 VALU/pair, issued at full wave
    // cost) that the old form needed.
    //   pass 1: lanes 0..32 -> row A edge k=lane (idx = lane);
    //           lanes 33..63 -> row B edge k=lane-33 (idx = lane+99,
    //           since rowB edge k sits at mU*33 + 132 + k).
    //   pass 2: lanes 31,32 -> row B edges 31,32 (idx = lane+132).
    // NOTE (r11 bug fix): mU = mRowA ALREADY includes gbase — the dst plane
    // writes are fA/fB directly, NOT gbase+fA (that double-count was the
    // r11 absmax=130560 failure).
    // dist/mask recomputed exactly as numpy fp32 (rn ops, same order) —
    // bit-identical given identical (src,dst).
    auto emitPair = [&](uint32_t vA, uint32_t vB, const float4 pA,
                        const float4 pB, int mRowA) {
        const int mU = __builtin_amdgcn_readfirstlane(mRowA);
        float* const b0 = out + (size_t)mU * KNN;            // src plane
        float* const b1 = b0 + (size_t)EDGES;                // dst plane
        float* const b2 = b0 + 2 * (size_t)EDGES;            // dist plane
        float* const b3 = b0 + 3 * (size_t)EDGES;            // mask plane
        const float fA = (float)mU;                          // uniform cvt (exact: mU < 2^24)
        const float fB = (float)(mU + WAVES_PER_BLOCK);      // uniform cvt

        const bool isA = (lane < KNN);
        const uint32_t vBs = (uint32_t)__builtin_amdgcn_ds_bpermute(
            (((lane - KNN) & 63) << 2), (int)vB);

        {   // pass 1 — full wave, 64 edges
            const uint32_t key = isA ? vA : vBs;
            const int      idx = isA ? lane : (lane + 99);
            const float cx = isA ? pA.x : pB.x;
            const float cy = isA ? pA.y : pB.y;
            const float cz = isA ? pA.z : pB.z;
            const int kept = (int)(key & 0x1FFu);
            const float4 q = spt[kept];
            const float dx = __fsub_rn(q.x, cx);
            const float dy = __fsub_rn(q.y, cy);
            const float dz = __fsub_rn(q.z, cz);
            const float ss = __fadd_rn(__fadd_rn(__fmul_rn(dx, dx),
                                                 __fmul_rn(dy, dy)),
                                       __fmul_rn(dz, dz));
            const float dist  = (ss > 0.0f) ? __fsqrt_rn(ss) : 0.0f;
            const float maskv = (dist <= RADIUS_F) ? 1.0f : 0.0f;
            b0[idx] = (float)(gbase + kept);
            b1[idx] = isA ? fA : fB;
            b2[idx] = dist;
            b3[idx] = maskv;
        }
        if ((unsigned)(lane - 31) < 2u) {   // pass 2 — row B ranks 31,32
            const int idx  = lane + 132;
            const int kept = (int)(vB & 0x1FFu);
            const float4 q = spt[kept];
            const float dx = __fsub_rn(q.x, pB.x);
            const float dy = __fsub_rn(q.y, pB.y);
            const float dz = __fsub_rn(q.z, pB.z);
            const float ss = __fadd_rn(__fadd_rn(__fmul_rn(dx, dx),
                                                 __fmul_rn(dy, dy)),
                                       __fmul_rn(dz, dz));
            const float dist  = (ss > 0.0f) ? __fsqrt_rn(ss) : 0.0f;
            const float maskv = (dist <= RADIUS_F) ? 1.0f : 0.0f;
            b0[idx] = (float)(gbase + kept);
            b1[idx] = fB;
            b2[idx] = dist;
            b3[idx] = maskv;
        }
    };

    // Rare path (>64 survivors with the 16-bit-rounded head pivot, <1% of
    // rows): keys are UNIQUE (candidate id in low 9 bits), so the minimal
    // valid pivot has element-count EXACTLY 33. Exact u32 bisection.
    auto refineRow = [&](const uint32_t* sk, uint32_t& P,
                         uint32_t& cnt, uint32_t& incl, uint32_t& total) {
        uint32_t lo = 0u, hi = P;
        while (lo < hi) {
            const uint32_t mid = lo + ((hi - lo) >> 1);
            uint32_t c = 0;
            #pragma unroll
            for (int j = 0; j < 8; ++j) c += (sk[j] <= mid) ? 1u : 0u;
            const uint32_t t =
                (uint32_t)__builtin_amdgcn_readlane((int)wave_incl_scan(c), 63);
            if (t < KNN) lo = mid + 1; else hi = mid;
        }
        P = hi;
        cnt = 0;
        #pragma unroll
        for (int j = 0; j < 8; ++j) cnt += (sk[j] <= P) ? 1u : 0u;
        incl  = wave_incl_scan(cnt);   // lane63 total == 33 by key uniqueness
        total = KNN;
    };

    // 8 outer iterations × (4 waves × 2 rows) = 64 rows per block.
    #pragma unroll 1
    for (int it = 0; it < ROWS_PER_BLOCK / (WAVES_PER_BLOCK * 2); ++it) {
        const int mA = slice * ROWS_PER_BLOCK + it * (WAVES_PER_BLOCK * 2) + wave;
        const int mB = mA + WAVES_PER_BLOCK;

        const float4 pa = spt[mA];
        const float4 pb = spt[mB];

        // --- distance/key phase, rows A,B packed as v_pk f32x2 -------------
        // Lane holds candidates n = lane + 64*j for BOTH rows (shared q load).
        // u32 key = (d2bits & ~0x1FF) | n: candidate id in low 9 bits,
        // 512-ulp d2 truncation (tie flips tolerated; dist recomputed
        // exactly). No max(d2,0): self-edge d2 is exactly +0 by identical
        // fma-chain construction; a negative near-zero d2 (coincident
        // points, ~never on this data) sorts to the tail — same tolerated
        // tie class. Packed ops are IEEE-RN per component.
        uint32_t sA[8], sB[8];
        {
#ifdef HAVE_PKFMA
            const f32x2 px = {pa.x, pb.x}, py = {pa.y, pb.y};
            const f32x2 pz = {pa.z, pb.z}, pw = {pa.w, pb.w};
            const f32x2 m2 = {-2.0f, -2.0f};
#endif
            #pragma unroll
            for (int j = 0; j < 8; ++j) {
                const int n = lane + (j << 6);
                const float4 q = spt[n];
#ifdef HAVE_PKFMA
                const f32x2 qx = {q.x, q.x}, qy = {q.y, q.y};
                const f32x2 qz = {q.z, q.z}, qw = {q.w, q.w};
                const f32x2 dot = __builtin_elementwise_fma(px, qx,
                                  __builtin_elementwise_fma(py, qy, pz * qz));
                const f32x2 d2  = __builtin_elementwise_fma(m2, dot, pw + qw);
                const float d2A = d2[0];
                const float d2B = d2[1];
#else
                const float dotA = __builtin_fmaf(pa.x, q.x,
                                   __builtin_fmaf(pa.y, q.y, __fmul_rn(pa.z, q.z)));
                const float dotB = __builtin_fmaf(pb.x, q.x,
                                   __builtin_fmaf(pb.y, q.y, __fmul_rn(pb.z, q.z)));
                const float d2A = __builtin_fmaf(-2.0f, dotA, __fadd_rn(pa.w, q.w));
                const float d2B = __builtin_fmaf(-2.0f, dotB, __fadd_rn(pb.w, q.w));
#endif
                // canonical (m&x)|(~m&y) -> v_bfi_b32
                sA[j] = (0xFFFFFE00u & __float_as_uint(d2A)) | (0x000001FFu & (uint32_t)n);
                sB[j] = (0xFFFFFE00u & __float_as_uint(d2B)) | (0x000001FFu & (uint32_t)n);
            }
        }

        // --- per-lane heads -------------------------------------------------
        uint32_t hA = sA[0], hB = sB[0];
        #pragma unroll
        for (int j = 1; j < 8; ++j) {
            hA = sA[j] < hA ? sA[j] : hA;
            hB = sB[j] < hB ? sB[j] : hB;
        }

        // --- pivot = 33rd-smallest head, via ONE PACKED 16-bit head-sort ----
        // Both rows' heads truncated to their top 16 bits and packed into one
        // register (lo = row A, hi = row B); a single bitonic sort64 with
        // v_pk_min/max_u16 sorts both rows at once (same lane predicates).
        // floor-truncation is monotone => sorted16[32] = trunc16(h_(33));
        // P = (trunc16(h_(33)) << 16) | 0xFFFF >= h_(33), so count(<=P) >= 33
        // still holds. The 2^16-ulp round-up adds ~0.3 expected survivors
        // (d2-density near cutoff); >64 overflow handled by exact refineRow.
        uint32_t hP = (hB & 0xFFFF0000u) | (hA >> 16);
        hP = bsort64pk(hP, l1, l2, l4, l8, l16, l32);
        const uint32_t s32 = (uint32_t)__builtin_amdgcn_readlane((int)hP, 32);
        uint32_t PA = (s32 << 16) | 0xFFFFu;
        uint32_t PB = (s32 & 0xFFFF0000u) | 0xFFFFu;

        // --- dual count + ONE packed scan (halves can't carry: totals<=512) -
        uint32_t cntA = 0, cntB = 0;
        #pragma unroll
        for (int j = 0; j < 8; ++j) {
            cntA += (sA[j] <= PA) ? 1u : 0u;
            cntB += (sB[j] <= PB) ? 1u : 0u;
        }
        const uint32_t cP   = wave_incl_scan(cntA + (cntB << 16));
        const uint32_t totP = (uint32_t)__builtin_amdgcn_readlane((int)cP, 63);
        uint32_t inclA = cP & 0xFFFFu;
        uint32_t inclB = cP >> 16;
        uint32_t totalA = totP & 0xFFFFu;
        uint32_t totalB = totP >> 16;

        // rare overflow: tighten to the exact minimal pivot (=> exactly 33)
        if (__builtin_expect(totalA > 64u, 0)) refineRow(sA, PA, cntA, inclA, totalA);
        if (__builtin_expect(totalB > 64u, 0)) refineRow(sB, PB, cntB, inclB, totalB);

        const int rA = wave;
        const int rB = wave + WAVES_PER_BLOCK;
        const int mRowA = gbase + mA;

        // --- conditional (exec-masked) scatter: survivors only, dense unique
        // destinations, bank-stride 1 (u32). NO padding-init writes: lanes
        // beyond `total` are masked to +INF on the read below instead (2 VALU
        // replace 2 LDS writes and shorten the scatter->read drain).
        uint32_t dA = inclA - cntA;
        uint32_t dB = inclB - cntB;
        #pragma unroll
        for (int j = 0; j < 8; ++j) {
            const bool svA = (sA[j] <= PA);
            const bool svB = (sB[j] <= PB);
            if (svA) slots[rA][dA] = sA[j];
            if (svB) slots[rB][dB] = sB[j];
            dA += svA ? 1u : 0u;
            dB += svB ? 1u : 0u;
        }

        // same-wave producer/consumer: lgkmcnt ordering only, no barrier.
        // Positions >= total hold stale data — masked to +INF (sorts to tail).
        const uint32_t rdA = slots[rA][lane];
        const uint32_t rdB = slots[rB][lane];
        uint32_t vA = ((uint32_t)lane < totalA) ? rdA : 0xFFFFFFFFu;
        uint32_t vB = ((uint32_t)lane < totalB) ? rdB : 0xFFFFFFFFu;
        bsort64d(vA, vB, l1, l2, l4, l8, l16, l32);

        emitPair(vA, vB, pa, pb, mRowA);
    }
}

extern "C" void kernel_launch(void* const* d_in, const int* in_sizes, int n_in,
                              void* d_out, int out_size, void* d_ws, size_t ws_size,
                              hipStream_t stream) {
    (void)in_sizes; (void)n_in; (void)out_size; (void)d_ws; (void)ws_size;
    const float* pos = (const float*)d_in[0];   // d_in[1] (batch) implied by layout
    float*       out = (float*)d_out;
    hipLaunchKernelGGL(InteractionModule_50483045597845_kernel,
                       dim3(BATCH * BLOCKS_PER_GRAPH), dim3(THREADS), 0, stream,
                       pos, out);
}